// Round 16
// baseline (155.550 us; speedup 1.0000x reference)
//
#include <hip/hip_runtime.h>

#define N_NODES 50000
#define N_EDGES 800000
#define IN_F    128
#define OUT_F   64
#define N_HEADS 4
#define NEG_SLOPE 0.2f
#define EPS 1e-12f

#define NODE_BLOCKS 782   // ceil(50000 / 64) for the MFMA part
#define NB    391         // buckets of 128 rows: bucket = row >> 7
#define CHUNK 4096        // edges per histogram/scatter chunk
#define NCH   196         // 196*4096 = 802816 >= 800000
#define S2N   (NB * NCH)  // 76636 histogram entries
#define S2B   75          // scan blocks: 75*1024 = 76800 >= S2N

typedef __attribute__((ext_vector_type(8))) short bf16x8;
typedef __attribute__((ext_vector_type(4))) float f32x4;

// bf16 helpers (RNE)
__device__ __forceinline__ unsigned short f2bf(float f) {
    unsigned int u = __float_as_uint(f);
    u += 0x7FFFu + ((u >> 16) & 1u);
    return (unsigned short)(u >> 16);
}
__device__ __forceinline__ float bf_lo(unsigned u) { return __uint_as_float(u << 16); }
__device__ __forceinline__ float bf_hi(unsigned u) { return __uint_as_float(u & 0xFFFF0000u); }

// Device-scope grid barrier for a co-resident grid (391 blocks <= capacity).
// ctr must be zeroed by a PRIOR kernel in the same stream each launch.
__device__ __forceinline__ void gbar(int* ctr, int nblk) {
    __syncthreads();
    if (threadIdx.x == 0) {
        __threadfence();
        atomicAdd(ctr, 1);
        while (__hip_atomic_load(ctr, __ATOMIC_RELAXED, __HIP_MEMORY_SCOPE_AGENT) < nblk)
            __builtin_amdgcn_s_sleep(1);
        __threadfence();
    }
    __syncthreads();
}

// ---------------------------------------------------------------------------
// K1 fused: blocks [0, NCH): per-chunk bucket histogram (LDS atomics) +
// block 0 zeroes the grid-barrier counters for k_build;
// blocks [NCH, NCH+NODE_BLOCKS): h = x@W via MFMA bf16 with fused el/er
// epilogue. W converted f32->bf16 in-block.
// LDS tiles bf16 [64][128], XOR-swizzled (byte ^= (row&7)<<4).
// MFMA C/D: col = l&15, row = (l>>4)*4 + reg  [verified mapping].
// ---------------------------------------------------------------------------
__global__ __launch_bounds__(256) void k_hist_gemm(
    const float* __restrict__ x, const float* __restrict__ W,
    const float* __restrict__ a_l, const float* __restrict__ a_r,
    const int* __restrict__ row, int* __restrict__ histG,
    unsigned short* __restrict__ h_bf,
    float* __restrict__ el, float* __restrict__ er,
    int* __restrict__ sync_ctr)
{
    __shared__ int hist[NB];
    __shared__ unsigned short xs[64 * 128];   // 16 KB, swizzled
    __shared__ unsigned short wsh[64 * 128];  // 16 KB, swizzled
    const int tid = threadIdx.x;

    if (blockIdx.x < NCH) {
        // ---- histogram part ----
        const int ch = blockIdx.x;
        if (ch == 0 && tid < 8) sync_ctr[tid] = 0;   // reset barrier counters
        for (int i = tid; i < NB; i += 256) hist[i] = 0;
        __syncthreads();
        const int e0 = ch * CHUNK + tid * 16;
        #pragma unroll
        for (int q = 0; q < 4; ++q) {
            const int e = e0 + q * 4;
            if (e + 3 < N_EDGES) {
                int4 a = *(const int4*)(row + e);
                atomicAdd(&hist[a.x >> 7], 1); atomicAdd(&hist[a.y >> 7], 1);
                atomicAdd(&hist[a.z >> 7], 1); atomicAdd(&hist[a.w >> 7], 1);
            } else {
                #pragma unroll
                for (int j = 0; j < 4; ++j)
                    if (e + j < N_EDGES) atomicAdd(&hist[row[e + j] >> 7], 1);
            }
        }
        __syncthreads();
        for (int i = tid; i < NB; i += 256) histG[i * NCH + ch] = hist[i];
        return;
    }

    // ---- GEMM part ----
    const int node0 = (blockIdx.x - NCH) * 64;

    {   // stage W transposed+bf16+swizzled: thread t: col c = t&63, kq = t>>6
        const int c  = tid & 63;
        const int kq = tid >> 6;          // k-range kq*32 .. +31
        #pragma unroll
        for (int kb = 0; kb < 32; kb += 8) {
            unsigned pk[4];
            #pragma unroll
            for (int i = 0; i < 4; ++i) {
                const int k = kq * 32 + kb + 2 * i;
                const float v0 = W[k * OUT_F + c];        // wave-coalesced 256B
                const float v1 = W[(k + 1) * OUT_F + c];
                pk[i] = (unsigned)f2bf(v0) | ((unsigned)f2bf(v1) << 16);
            }
            const int cb = (kq * 32 + kb) * 2;            // byte col offset
            *(uint4*)((char*)wsh + c * 256 + (cb ^ ((c & 7) << 4))) =
                make_uint4(pk[0], pk[1], pk[2], pk[3]);
        }
    }
    {   // stage x rows (f32 -> bf16)
        const int r = tid >> 2;
        const int c0 = (tid & 3) * 32;
        const int node = node0 + r;
        unsigned int pk[16];
        if (node < N_NODES) {
            const float* src = x + (size_t)node * IN_F + c0;
            #pragma unroll
            for (int i = 0; i < 8; ++i) {
                float4 v = *(const float4*)(src + 4 * i);
                pk[2 * i + 0] = (unsigned)f2bf(v.x) | ((unsigned)f2bf(v.y) << 16);
                pk[2 * i + 1] = (unsigned)f2bf(v.z) | ((unsigned)f2bf(v.w) << 16);
            }
        } else {
            #pragma unroll
            for (int i = 0; i < 16; ++i) pk[i] = 0;
        }
        #pragma unroll
        for (int q = 0; q < 4; ++q) {
            int cb = c0 * 2 + q * 16;
            *(uint4*)((char*)xs + r * 256 + (cb ^ ((r & 7) << 4))) =
                make_uint4(pk[4 * q], pk[4 * q + 1], pk[4 * q + 2], pk[4 * q + 3]);
        }
    }
    __syncthreads();

    const int w  = tid >> 6, l = tid & 63;
    const int lr = l & 15, lg = l >> 4;
    const int arow = w * 16 + lr;

    bf16x8 afr[4];
    #pragma unroll
    for (int t = 0; t < 4; ++t) {
        int cb = t * 64 + lg * 16;
        afr[t] = *(const bf16x8*)((char*)xs + arow * 256 + (cb ^ ((arow & 7) << 4)));
    }

    const f32x4 zero = {0.f, 0.f, 0.f, 0.f};
    f32x4 acc[4] = {zero, zero, zero, zero};
    #pragma unroll
    for (int nt = 0; nt < 4; ++nt) {
        const int brow = nt * 16 + lr;
        #pragma unroll
        for (int t = 0; t < 4; ++t) {
            int cb = t * 64 + lg * 16;
            bf16x8 bfr = *(const bf16x8*)((char*)wsh + brow * 256 + (cb ^ ((brow & 7) << 4)));
            acc[nt] = __builtin_amdgcn_mfma_f32_16x16x32_bf16(afr[t], bfr, acc[nt], 0, 0, 0);
        }
    }

    #pragma unroll
    for (int r = 0; r < 4; ++r) {
        const int node = node0 + w * 16 + lg * 4 + r;
        if (node < N_NODES) {
            #pragma unroll
            for (int nt = 0; nt < 4; ++nt)
                h_bf[(size_t)node * OUT_F + nt * 16 + lr] = f2bf(acc[nt][r]);
        }
    }

    float4 al4[4], ar4[4];
    #pragma unroll
    for (int nt = 0; nt < 4; ++nt) {
        al4[nt] = *(const float4*)(a_l + (size_t)(nt * 16 + lr) * N_HEADS);
        ar4[nt] = *(const float4*)(a_r + (size_t)(nt * 16 + lr) * N_HEADS);
    }
    #pragma unroll
    for (int r = 0; r < 4; ++r) {
        float4 pl = make_float4(0.f, 0.f, 0.f, 0.f);
        float4 pr = make_float4(0.f, 0.f, 0.f, 0.f);
        #pragma unroll
        for (int nt = 0; nt < 4; ++nt) {
            const float v = acc[nt][r];
            pl.x += v * al4[nt].x; pl.y += v * al4[nt].y;
            pl.z += v * al4[nt].z; pl.w += v * al4[nt].w;
            pr.x += v * ar4[nt].x; pr.y += v * ar4[nt].y;
            pr.z += v * ar4[nt].z; pr.w += v * ar4[nt].w;
        }
        #pragma unroll
        for (int off = 1; off < 16; off <<= 1) {
            pl.x += __shfl_xor(pl.x, off); pl.y += __shfl_xor(pl.y, off);
            pl.z += __shfl_xor(pl.z, off); pl.w += __shfl_xor(pl.w, off);
            pr.x += __shfl_xor(pr.x, off); pr.y += __shfl_xor(pr.y, off);
            pr.z += __shfl_xor(pr.z, off); pr.w += __shfl_xor(pr.w, off);
        }
        const int node = node0 + w * 16 + lg * 4 + r;
        if (lr == 0 && node < N_NODES) {
            *(float4*)(el + (size_t)node * N_HEADS) = pl;
            *(float4*)(er + (size_t)node * N_HEADS) = pr;
        }
    }
}

// ---------------------------------------------------------------------------
// K2 merged CSR build: 391 co-resident blocks, 3 phases with device barriers.
//  A (blocks 0..74):  exclusive scan of histG -> scanHist + blocksum
//  B (blocks 0..195): per-chunk bucket-scatter into ebuf
//  C (all 391):       per-bucket row sort + exp weights -> rowptr, edata
// ---------------------------------------------------------------------------
__global__ __launch_bounds__(256, 2) void k_build(
    const int* __restrict__ row, const int* __restrict__ col,
    const int* __restrict__ histG, int* __restrict__ scanHist,
    int* __restrict__ blocksum,
    const float* __restrict__ el, const float* __restrict__ er,
    unsigned* __restrict__ ebuf, int* __restrict__ rowptr,
    uint4* __restrict__ edata, int* __restrict__ sync_ctr)
{
    __shared__ int off[NB];
    __shared__ int bsum[S2B];
    __shared__ float4 elv[128];
    __shared__ int cnt[128];
    __shared__ int wsum4[4];
    const int blk = blockIdx.x;
    const int t = threadIdx.x;

    // ---- Phase A: scan ----
    if (blk < S2B) {
        const int base = blk * 1024 + t * 4;
        int4 d = make_int4(0, 0, 0, 0);
        if (base + 3 < S2N) d = *(const int4*)(histG + base);
        else {
            if (base + 0 < S2N) d.x = histG[base + 0];
            if (base + 1 < S2N) d.y = histG[base + 1];
            if (base + 2 < S2N) d.z = histG[base + 2];
            if (base + 3 < S2N) d.w = histG[base + 3];
        }
        const int tsum = d.x + d.y + d.z + d.w;
        const int lane = t & 63, wave = t >> 6;
        int inc = tsum;
        #pragma unroll
        for (int off2 = 1; off2 < 64; off2 <<= 1) {
            int v = __shfl_up(inc, off2);
            if (lane >= off2) inc += v;
        }
        if (lane == 63) wsum4[wave] = inc;
        __syncthreads();
        int woff = 0;
        #pragma unroll
        for (int w = 0; w < 4; ++w) woff += (w < wave) ? wsum4[w] : 0;
        const int ex = woff + inc - tsum;
        int4 o;
        o.x = ex; o.y = ex + d.x; o.z = o.y + d.y; o.w = o.z + d.z;
        if (base + 3 < S2N) *(int4*)(scanHist + base) = o;
        else {
            if (base + 0 < S2N) scanHist[base + 0] = o.x;
            if (base + 1 < S2N) scanHist[base + 1] = o.y;
            if (base + 2 < S2N) scanHist[base + 2] = o.z;
            if (base + 3 < S2N) scanHist[base + 3] = o.w;
        }
        if (t == 0) blocksum[blk] = wsum4[0] + wsum4[1] + wsum4[2] + wsum4[3];
    }

    gbar(&sync_ctr[0], NB);

    // ---- blocksum prefix (needed by B and C) ----
    if (t < S2B) bsum[t] = blocksum[t];
    __syncthreads();
    if (t == 0) {
        int s = 0;
        for (int i = 0; i < S2B; ++i) { int v = bsum[i]; bsum[i] = s; s += v; }
    }
    __syncthreads();

    // ---- Phase B: scatter ----
    if (blk < NCH) {
        const int ch = blk;
        for (int i = t; i < NB; i += 256) {
            const int idx = i * NCH + ch;
            off[i] = scanHist[idx] + bsum[idx >> 10];
        }
        __syncthreads();
        const int e0 = ch * CHUNK;
        #pragma unroll
        for (int k = 0; k < 16; ++k) {
            const int e = e0 + t + k * 256;
            if (e < N_EDGES) {
                const int r = row[e], c = col[e];
                const int pos = atomicAdd(&off[r >> 7], 1);
                ebuf[pos] = ((unsigned)(r & 127) << 17) | (unsigned)c;
            }
        }
    }

    gbar(&sync_ctr[1], NB);

    // ---- Phase C: per-bucket finalize ----
    {
        const int b = blk;
        const int node0 = b << 7;
        const int i0 = b * NCH;
        const int base = scanHist[i0] + bsum[i0 >> 10];
        int end;
        if (b < NB - 1) {
            const int i1 = (b + 1) * NCH;
            end = scanHist[i1] + bsum[i1 >> 10];
        } else end = N_EDGES;

        if (t < 128) {
            const int node = node0 + t;
            elv[t] = (node < N_NODES) ? *(const float4*)(el + node * 4)
                                      : make_float4(0.f, 0.f, 0.f, 0.f);
            cnt[t] = 0;
        }
        __syncthreads();
        for (int i = base + t; i < end; i += 256)
            atomicAdd(&cnt[ebuf[i] >> 17], 1);
        __syncthreads();

        int inc = 0, val = 0;
        const int lane = t & 63, wave = t >> 6;
        if (t < 128) {
            val = cnt[t];
            inc = val;
            #pragma unroll
            for (int off2 = 1; off2 < 64; off2 <<= 1) {
                int v = __shfl_up(inc, off2);
                if (lane >= off2) inc += v;
            }
            if (lane == 63) wsum4[wave] = inc;
        }
        __syncthreads();
        int excl = 0;
        if (t < 128) {
            const int woff = (wave == 1) ? wsum4[0] : 0;
            excl = base + woff + inc - val;
            const int node = node0 + t;
            if (node < N_NODES) rowptr[node] = excl;
        }
        if (b == NB - 1 && t == 0) rowptr[N_NODES] = N_EDGES;
        __syncthreads();
        if (t < 128) cnt[t] = excl;   // reuse as write cursors
        __syncthreads();

        for (int i = base + t; i < end; i += 256) {
            const unsigned p = ebuf[i];
            const int r = p >> 17;
            const int c = (int)(p & 0x1FFFFu);
            const int pos = atomicAdd(&cnt[r], 1);
            const float4 e4 = elv[r];
            const float4 r4 = *(const float4*)(er + ((unsigned)c << 2));
            float s0 = e4.x + r4.x, s1 = e4.y + r4.y;
            float s2 = e4.z + r4.z, s3 = e4.w + r4.w;
            s0 = s0 > 0.f ? s0 : NEG_SLOPE * s0;
            s1 = s1 > 0.f ? s1 : NEG_SLOPE * s1;
            s2 = s2 > 0.f ? s2 : NEG_SLOPE * s2;
            s3 = s3 > 0.f ? s3 : NEG_SLOPE * s3;
            const unsigned w01 = (unsigned)f2bf(__expf(s0)) | ((unsigned)f2bf(__expf(s1)) << 16);
            const unsigned w23 = (unsigned)f2bf(__expf(s2)) | ((unsigned)f2bf(__expf(s3)) << 16);
            edata[pos] = make_uint4((unsigned)c, w01, w23, 0u);
        }
    }
}

// ---------------------------------------------------------------------------
// K5: gather — one wave per node; 4 x 16-lane groups, 2 edges per group per
// iteration (8/wave-iter), 1-ahead pipeline, branch-free clamped loads.
// Edge record: uint4 {col, w01 bf16x2, w23 bf16x2, 0} (L2-warm from k_build
// — plain loads). out stores nontemporal (never re-read).
// ---------------------------------------------------------------------------
__global__ __launch_bounds__(256) void k_gather(
    const int* __restrict__ rowptr, const uint4* __restrict__ edata,
    const unsigned short* __restrict__ h_bf, const float* __restrict__ b,
    float* __restrict__ out)
{
    int n = blockIdx.x * 4 + (threadIdx.x >> 6);
    if (n >= N_NODES) return;
    const int lane = threadIdx.x & 63;
    const int g    = lane >> 4;    // group == output head at the end
    const int fq   = lane & 15;    // feature quad: feats fq*4 .. +3

    const int s0 = rowptr[n], s1 = rowptr[n + 1];
    const int nit = (s1 - s0 + 7) >> 3;

    float acc[4][4];
    #pragma unroll
    for (int hd = 0; hd < 4; ++hd)
        #pragma unroll
        for (int f = 0; f < 4; ++f) acc[hd][f] = 0.f;
    float den[4] = {0.f, 0.f, 0.f, 0.f};

    if (nit > 0) {   // s1 > s0 guaranteed inside
#define LOADE(ii, E0, E1)                                   \
        {                                                   \
            const int j0 = s0 + (ii) * 8 + 2 * g;           \
            const int j1 = j0 + 1;                          \
            E0 = edata[j0 < s1 ? j0 : s1 - 1];              \
            E1 = edata[j1 < s1 ? j1 : s1 - 1];              \
            if (j0 >= s1) { E0.y = 0u; E0.z = 0u; }         \
            if (j1 >= s1) { E1.y = 0u; E1.z = 0u; }         \
        }
#define LOADH(E, H)                                                              \
        H = *(const uint2*)(h_bf + (((E.x & 0xFFFFu) << 6) + ((unsigned)fq << 2)));
#define COMP1(E, H)                                                              \
        {                                                                        \
            const float w0 = bf_lo(E.y), w1 = bf_hi(E.y);                        \
            const float w2 = bf_lo(E.z), w3 = bf_hi(E.z);                        \
            const float f0 = bf_lo(H.x), f1 = bf_hi(H.x);                        \
            const float f2 = bf_lo(H.y), f3 = bf_hi(H.y);                        \
            den[0] += w0; den[1] += w1; den[2] += w2; den[3] += w3;              \
            acc[0][0] += w0 * f0; acc[0][1] += w0 * f1;                          \
            acc[0][2] += w0 * f2; acc[0][3] += w0 * f3;                          \
            acc[1][0] += w1 * f0; acc[1][1] += w1 * f1;                          \
            acc[1][2] += w1 * f2; acc[1][3] += w1 * f3;                          \
            acc[2][0] += w2 * f0; acc[2][1] += w2 * f1;                          \
            acc[2][2] += w2 * f2; acc[2][3] += w2 * f3;                          \
            acc[3][0] += w3 * f0; acc[3][1] += w3 * f1;                          \
            acc[3][2] += w3 * f2; acc[3][3] += w3 * f3;                          \
        }

        uint4 a0, a1, b0, b1;
        uint2 ha0, ha1, hb0, hb1;
        LOADE(0, a0, a1);
        LOADH(a0, ha0); LOADH(a1, ha1);

        for (int it = 0; it < nit; ++it) {
            LOADE(it + 1, b0, b1);
            LOADH(b0, hb0); LOADH(b1, hb1);
            COMP1(a0, ha0);
            COMP1(a1, ha1);
            a0 = b0; a1 = b1; ha0 = hb0; ha1 = hb1;
        }
#undef LOADE
#undef LOADH
#undef COMP1
    }

    // reduce partials across the 4 groups (lanes xor 16, 32)
    #pragma unroll
    for (int hd = 0; hd < 4; ++hd) {
        float v = den[hd];
        v += __shfl_xor(v, 16); v += __shfl_xor(v, 32);
        den[hd] = v;
        #pragma unroll
        for (int f = 0; f < 4; ++f) {
            float u = acc[hd][f];
            u += __shfl_xor(u, 16); u += __shfl_xor(u, 32);
            acc[hd][f] = u;
        }
    }

    const float dg = g == 0 ? den[0] : g == 1 ? den[1] : g == 2 ? den[2] : den[3];
    const float inv = 1.f / fmaxf(dg, EPS);
    f32x4 o;
    o.x = (g == 0 ? acc[0][0] : g == 1 ? acc[1][0] : g == 2 ? acc[2][0] : acc[3][0]);
    o.y = (g == 0 ? acc[0][1] : g == 1 ? acc[1][1] : g == 2 ? acc[2][1] : acc[3][1]);
    o.z = (g == 0 ? acc[0][2] : g == 1 ? acc[1][2] : g == 2 ? acc[2][2] : acc[3][2]);
    o.w = (g == 0 ? acc[0][3] : g == 1 ? acc[1][3] : g == 2 ? acc[2][3] : acc[3][3]);

    const float4 bias = *(const float4*)(b + fq * 4);
    o.x = o.x * inv + bias.x;
    o.y = o.y * inv + bias.y;
    o.z = o.z * inv + bias.z;
    o.w = o.w * inv + bias.w;
    __builtin_nontemporal_store(o,
        (f32x4*)(out + (size_t)n * (N_HEADS * OUT_F) + g * 64 + fq * 4));
}

extern "C" void kernel_launch(void* const* d_in, const int* in_sizes, int n_in,
                              void* d_out, int out_size, void* d_ws, size_t ws_size,
                              hipStream_t stream)
{
    const float* x   = (const float*)d_in[0];
    const int*   ei  = (const int*)d_in[1];
    const float* W   = (const float*)d_in[2];
    const float* a_l = (const float*)d_in[3];
    const float* a_r = (const float*)d_in[4];
    const float* b   = (const float*)d_in[5];
    float* out = (float*)d_out;

    char* ws = (char*)d_ws;
    unsigned short* h_bf = (unsigned short*)(ws);          //  6,400,000 B
    float*    el       = (float*)   (ws +  6400000);       //    800,000 B
    float*    er       = (float*)   (ws +  7200000);       //    800,000 B
    int*      histG    = (int*)     (ws +  8000000);       //    306,544 B
    int*      scanHist = (int*)     (ws +  8306544);       //    306,544 B
    int*      blocksum = (int*)     (ws +  8613088);       //      1,024 B
    unsigned* ebuf     = (unsigned*)(ws +  8614112);       //  3,200,000 B
    int*      rowptr   = (int*)     (ws + 11814112);       //    200,016 B
    uint4*    edata    = (uint4*)   (ws + 12014128);       // 12,800,016 B
    int*      sync_ctr = (int*)     (ws + 24814144);       //         32 B
    // total: 24,814,176 B

    const int* row = ei;
    const int* col = ei + N_EDGES;

    k_hist_gemm<<<NCH + NODE_BLOCKS, 256, 0, stream>>>(
                   x, W, a_l, a_r, row, histG, h_bf, el, er, sync_ctr);
    k_build    <<<NB, 256, 0, stream>>>(
                   row, col, histG, scanHist, blocksum, el, er,
                   ebuf, rowptr, edata, sync_ctr);
    k_gather   <<<N_NODES / 4, 256, 0, stream>>>(rowptr, edata, h_bf, b, out);
}

// Round 17
// 76.787 us; speedup vs baseline: 2.0257x; 2.0257x over previous
//
#include <hip/hip_runtime.h>

#define N_NODES 50000
#define N_EDGES 800000
#define IN_F    128
#define OUT_F   64
#define N_HEADS 4
#define NEG_SLOPE 0.2f
#define EPS 1e-12f

#define NODE_BLOCKS 782   // ceil(50000 / 64) for the MFMA part
#define NB    391         // buckets of 128 rows: bucket = row >> 7
#define CHUNK 4096        // edges per histogram/scatter chunk
#define NCH   196         // 196*4096 = 802816 >= 800000
#define S2N   (NB * NCH)  // 76636 histogram entries
#define S2B   75          // scan blocks: 75*1024 = 76800 >= S2N
#define GATHER_LB 12500   // logical gather blocks = N_NODES/4
#define GATHER_PB 12544   // physical (padded to cover the swizzle range)

typedef __attribute__((ext_vector_type(8))) short bf16x8;
typedef __attribute__((ext_vector_type(4))) float f32x4;

// bf16 helpers (RNE)
__device__ __forceinline__ unsigned short f2bf(float f) {
    unsigned int u = __float_as_uint(f);
    u += 0x7FFFu + ((u >> 16) & 1u);
    return (unsigned short)(u >> 16);
}
__device__ __forceinline__ float bf_lo(unsigned u) { return __uint_as_float(u << 16); }
__device__ __forceinline__ float bf_hi(unsigned u) { return __uint_as_float(u & 0xFFFF0000u); }

// ---------------------------------------------------------------------------
// K1 fused: blocks [0, NCH): per-chunk bucket histogram (LDS atomics);
// blocks [NCH, NCH+NODE_BLOCKS): h = x@W via MFMA bf16 with fused el/er
// epilogue. W converted f32->bf16 in-block (no prep pass).
// LDS tiles bf16 [64][128], XOR-swizzled (byte ^= (row&7)<<4).
// MFMA C/D: col = l&15, row = (l>>4)*4 + reg  [verified mapping].
// ---------------------------------------------------------------------------
__global__ __launch_bounds__(256) void k_hist_gemm(
    const float* __restrict__ x, const float* __restrict__ W,
    const float* __restrict__ a_l, const float* __restrict__ a_r,
    const int* __restrict__ row, int* __restrict__ histG,
    unsigned short* __restrict__ h_bf,
    float* __restrict__ el, float* __restrict__ er)
{
    __shared__ int hist[NB];
    __shared__ unsigned short xs[64 * 128];   // 16 KB, swizzled
    __shared__ unsigned short wsh[64 * 128];  // 16 KB, swizzled
    const int tid = threadIdx.x;

    if (blockIdx.x < NCH) {
        // ---- histogram part ----
        const int ch = blockIdx.x;
        for (int i = tid; i < NB; i += 256) hist[i] = 0;
        __syncthreads();
        const int e0 = ch * CHUNK + tid * 16;
        #pragma unroll
        for (int q = 0; q < 4; ++q) {
            const int e = e0 + q * 4;
            if (e + 3 < N_EDGES) {
                int4 a = *(const int4*)(row + e);
                atomicAdd(&hist[a.x >> 7], 1); atomicAdd(&hist[a.y >> 7], 1);
                atomicAdd(&hist[a.z >> 7], 1); atomicAdd(&hist[a.w >> 7], 1);
            } else {
                #pragma unroll
                for (int j = 0; j < 4; ++j)
                    if (e + j < N_EDGES) atomicAdd(&hist[row[e + j] >> 7], 1);
            }
        }
        __syncthreads();
        for (int i = tid; i < NB; i += 256) histG[i * NCH + ch] = hist[i];
        return;
    }

    // ---- GEMM part ----
    const int node0 = (blockIdx.x - NCH) * 64;

    {   // stage W transposed+bf16+swizzled: thread t: col c = t&63, kq = t>>6
        const int c  = tid & 63;
        const int kq = tid >> 6;          // k-range kq*32 .. +31
        #pragma unroll
        for (int kb = 0; kb < 32; kb += 8) {
            unsigned pk[4];
            #pragma unroll
            for (int i = 0; i < 4; ++i) {
                const int k = kq * 32 + kb + 2 * i;
                const float v0 = W[k * OUT_F + c];        // wave-coalesced 256B
                const float v1 = W[(k + 1) * OUT_F + c];
                pk[i] = (unsigned)f2bf(v0) | ((unsigned)f2bf(v1) << 16);
            }
            const int cb = (kq * 32 + kb) * 2;            // byte col offset
            *(uint4*)((char*)wsh + c * 256 + (cb ^ ((c & 7) << 4))) =
                make_uint4(pk[0], pk[1], pk[2], pk[3]);
        }
    }
    {   // stage x rows (f32 -> bf16)
        const int r = tid >> 2;
        const int c0 = (tid & 3) * 32;
        const int node = node0 + r;
        unsigned int pk[16];
        if (node < N_NODES) {
            const float* src = x + (size_t)node * IN_F + c0;
            #pragma unroll
            for (int i = 0; i < 8; ++i) {
                float4 v = *(const float4*)(src + 4 * i);
                pk[2 * i + 0] = (unsigned)f2bf(v.x) | ((unsigned)f2bf(v.y) << 16);
                pk[2 * i + 1] = (unsigned)f2bf(v.z) | ((unsigned)f2bf(v.w) << 16);
            }
        } else {
            #pragma unroll
            for (int i = 0; i < 16; ++i) pk[i] = 0;
        }
        #pragma unroll
        for (int q = 0; q < 4; ++q) {
            int cb = c0 * 2 + q * 16;
            *(uint4*)((char*)xs + r * 256 + (cb ^ ((r & 7) << 4))) =
                make_uint4(pk[4 * q], pk[4 * q + 1], pk[4 * q + 2], pk[4 * q + 3]);
        }
    }
    __syncthreads();

    const int w  = tid >> 6, l = tid & 63;
    const int lr = l & 15, lg = l >> 4;
    const int arow = w * 16 + lr;

    bf16x8 afr[4];
    #pragma unroll
    for (int t = 0; t < 4; ++t) {
        int cb = t * 64 + lg * 16;
        afr[t] = *(const bf16x8*)((char*)xs + arow * 256 + (cb ^ ((arow & 7) << 4)));
    }

    const f32x4 zero = {0.f, 0.f, 0.f, 0.f};
    f32x4 acc[4] = {zero, zero, zero, zero};
    #pragma unroll
    for (int nt = 0; nt < 4; ++nt) {
        const int brow = nt * 16 + lr;
        #pragma unroll
        for (int t = 0; t < 4; ++t) {
            int cb = t * 64 + lg * 16;
            bf16x8 bfr = *(const bf16x8*)((char*)wsh + brow * 256 + (cb ^ ((brow & 7) << 4)));
            acc[nt] = __builtin_amdgcn_mfma_f32_16x16x32_bf16(afr[t], bfr, acc[nt], 0, 0, 0);
        }
    }

    #pragma unroll
    for (int r = 0; r < 4; ++r) {
        const int node = node0 + w * 16 + lg * 4 + r;
        if (node < N_NODES) {
            #pragma unroll
            for (int nt = 0; nt < 4; ++nt)
                h_bf[(size_t)node * OUT_F + nt * 16 + lr] = f2bf(acc[nt][r]);
        }
    }

    float4 al4[4], ar4[4];
    #pragma unroll
    for (int nt = 0; nt < 4; ++nt) {
        al4[nt] = *(const float4*)(a_l + (size_t)(nt * 16 + lr) * N_HEADS);
        ar4[nt] = *(const float4*)(a_r + (size_t)(nt * 16 + lr) * N_HEADS);
    }
    #pragma unroll
    for (int r = 0; r < 4; ++r) {
        float4 pl = make_float4(0.f, 0.f, 0.f, 0.f);
        float4 pr = make_float4(0.f, 0.f, 0.f, 0.f);
        #pragma unroll
        for (int nt = 0; nt < 4; ++nt) {
            const float v = acc[nt][r];
            pl.x += v * al4[nt].x; pl.y += v * al4[nt].y;
            pl.z += v * al4[nt].z; pl.w += v * al4[nt].w;
            pr.x += v * ar4[nt].x; pr.y += v * ar4[nt].y;
            pr.z += v * ar4[nt].z; pr.w += v * ar4[nt].w;
        }
        #pragma unroll
        for (int off = 1; off < 16; off <<= 1) {
            pl.x += __shfl_xor(pl.x, off); pl.y += __shfl_xor(pl.y, off);
            pl.z += __shfl_xor(pl.z, off); pl.w += __shfl_xor(pl.w, off);
            pr.x += __shfl_xor(pr.x, off); pr.y += __shfl_xor(pr.y, off);
            pr.z += __shfl_xor(pr.z, off); pr.w += __shfl_xor(pr.w, off);
        }
        const int node = node0 + w * 16 + lg * 4 + r;
        if (lr == 0 && node < N_NODES) {
            *(float4*)(el + (size_t)node * N_HEADS) = pl;
            *(float4*)(er + (size_t)node * N_HEADS) = pr;
        }
    }
}

// ---------------------------------------------------------------------------
// S2a: per-block exclusive scan (1024 elems/block) of histG -> scanHist.
// Consumers (scatter, bucket) apply the blocksum prefix themselves.
// ---------------------------------------------------------------------------
__global__ __launch_bounds__(256) void k_scan2_local(
    const int* __restrict__ histG, int* __restrict__ scanHist,
    int* __restrict__ blocksum)
{
    __shared__ int wsum[4];
    const int t = threadIdx.x;
    const int base = blockIdx.x * 1024 + t * 4;

    int4 d = make_int4(0, 0, 0, 0);
    if (base + 3 < S2N) d = *(const int4*)(histG + base);
    else {
        if (base + 0 < S2N) d.x = histG[base + 0];
        if (base + 1 < S2N) d.y = histG[base + 1];
        if (base + 2 < S2N) d.z = histG[base + 2];
        if (base + 3 < S2N) d.w = histG[base + 3];
    }
    const int tsum = d.x + d.y + d.z + d.w;

    const int lane = t & 63, wave = t >> 6;
    int inc = tsum;
    #pragma unroll
    for (int off = 1; off < 64; off <<= 1) {
        int v = __shfl_up(inc, off);
        if (lane >= off) inc += v;
    }
    if (lane == 63) wsum[wave] = inc;
    __syncthreads();

    int woff = 0;
    #pragma unroll
    for (int w = 0; w < 4; ++w) woff += (w < wave) ? wsum[w] : 0;

    const int ex = woff + inc - tsum;
    int4 o;
    o.x = ex; o.y = ex + d.x; o.z = o.y + d.y; o.w = o.z + d.z;
    if (base + 3 < S2N) *(int4*)(scanHist + base) = o;
    else {
        if (base + 0 < S2N) scanHist[base + 0] = o.x;
        if (base + 1 < S2N) scanHist[base + 1] = o.y;
        if (base + 2 < S2N) scanHist[base + 2] = o.z;
        if (base + 3 < S2N) scanHist[base + 3] = o.w;
    }
    if (t == 0) blocksum[blockIdx.x] = wsum[0] + wsum[1] + wsum[2] + wsum[3];
}

// ---------------------------------------------------------------------------
// S3: bucket-scatter edges. Per chunk: LDS write cursors from scanHist +
// blocksum prefix (computed in LDS), LDS-atomic slot allocation, store
// packed (row&127)<<17 | col.
// ---------------------------------------------------------------------------
__global__ __launch_bounds__(256) void k_scatter(
    const int* __restrict__ row, const int* __restrict__ col,
    const int* __restrict__ scanHist, const int* __restrict__ blocksum,
    unsigned* __restrict__ ebuf)
{
    __shared__ int off[NB];
    __shared__ int bsum[S2B];
    const int ch = blockIdx.x;
    const int t = threadIdx.x;
    if (t < S2B) bsum[t] = blocksum[t];
    __syncthreads();
    if (t == 0) {
        int s = 0;
        for (int i = 0; i < S2B; ++i) { int v = bsum[i]; bsum[i] = s; s += v; }
    }
    __syncthreads();
    for (int i = t; i < NB; i += 256) {
        const int idx = i * NCH + ch;
        off[i] = scanHist[idx] + bsum[idx >> 10];
    }
    __syncthreads();
    const int e0 = ch * CHUNK;
    #pragma unroll
    for (int k = 0; k < 16; ++k) {
        const int e = e0 + t + k * 256;
        if (e < N_EDGES) {
            const int r = row[e], c = col[e];
            const int pos = atomicAdd(&off[r >> 7], 1);
            ebuf[pos] = ((unsigned)(r & 127) << 17) | (unsigned)c;
        }
    }
}

// ---------------------------------------------------------------------------
// S4: per-bucket CSR finalize. Count 128 local rows (LDS), scan, write
// rowptr; then scatter packed edge records {col, w01(bf16), w23(bf16), 0}
// into the bucket-local region (single block -> single XCD).
// ---------------------------------------------------------------------------
__global__ __launch_bounds__(256) void k_bucket(
    const unsigned* __restrict__ ebuf, const int* __restrict__ scanHist,
    const int* __restrict__ blocksum,
    const float* __restrict__ el, const float* __restrict__ er,
    int* __restrict__ rowptr, uint4* __restrict__ edata)
{
    __shared__ float4 elv[128];
    __shared__ int cnt[128];
    __shared__ int wsum2[2];
    __shared__ int bsum[S2B];
    const int b = blockIdx.x;
    const int t = threadIdx.x;
    const int node0 = b << 7;

    if (t < S2B) bsum[t] = blocksum[t];
    __syncthreads();
    if (t == 0) {
        int s = 0;
        for (int i = 0; i < S2B; ++i) { int v = bsum[i]; bsum[i] = s; s += v; }
    }
    __syncthreads();

    const int i0 = b * NCH;
    const int base = scanHist[i0] + bsum[i0 >> 10];
    int end;
    if (b < NB - 1) {
        const int i1 = (b + 1) * NCH;
        end = scanHist[i1] + bsum[i1 >> 10];
    } else end = N_EDGES;

    if (t < 128) {
        const int node = node0 + t;
        elv[t] = (node < N_NODES) ? *(const float4*)(el + node * 4)
                                  : make_float4(0.f, 0.f, 0.f, 0.f);
        cnt[t] = 0;
    }
    __syncthreads();
    for (int i = base + t; i < end; i += 256)
        atomicAdd(&cnt[ebuf[i] >> 17], 1);
    __syncthreads();

    int inc = 0, val = 0;
    const int lane = t & 63, wave = t >> 6;
    if (t < 128) {
        val = cnt[t];
        inc = val;
        #pragma unroll
        for (int off = 1; off < 64; off <<= 1) {
            int v = __shfl_up(inc, off);
            if (lane >= off) inc += v;
        }
        if (lane == 63) wsum2[wave] = inc;
    }
    __syncthreads();
    int excl = 0;
    if (t < 128) {
        const int woff = (wave == 1) ? wsum2[0] : 0;
        excl = base + woff + inc - val;
        const int node = node0 + t;
        if (node < N_NODES) rowptr[node] = excl;
    }
    if (b == NB - 1 && t == 0) rowptr[N_NODES] = N_EDGES;
    __syncthreads();
    if (t < 128) cnt[t] = excl;   // reuse as write cursors
    __syncthreads();

    for (int i = base + t; i < end; i += 256) {
        const unsigned p = ebuf[i];
        const int r = p >> 17;
        const int c = (int)(p & 0x1FFFFu);
        const int pos = atomicAdd(&cnt[r], 1);
        const float4 e4 = elv[r];
        const float4 r4 = *(const float4*)(er + ((unsigned)c << 2));
        float s0 = e4.x + r4.x, s1 = e4.y + r4.y;
        float s2 = e4.z + r4.z, s3 = e4.w + r4.w;
        s0 = s0 > 0.f ? s0 : NEG_SLOPE * s0;
        s1 = s1 > 0.f ? s1 : NEG_SLOPE * s1;
        s2 = s2 > 0.f ? s2 : NEG_SLOPE * s2;
        s3 = s3 > 0.f ? s3 : NEG_SLOPE * s3;
        const unsigned w01 = (unsigned)f2bf(__expf(s0)) | ((unsigned)f2bf(__expf(s1)) << 16);
        const unsigned w23 = (unsigned)f2bf(__expf(s2)) | ((unsigned)f2bf(__expf(s3)) << 16);
        edata[pos] = make_uint4((unsigned)c, w01, w23, 0u);
    }
}

// ---------------------------------------------------------------------------
// K5: gather — one wave per node; 4 x 16-lane groups, 2 edges per group per
// iteration (8/wave-iter), 1-ahead pipeline, branch-free clamped loads.
// Edge record: uint4 {col, w01 bf16x2, w23 bf16x2, 0} (plain loads: L2-warm
// from k_bucket). out stores nontemporal (never re-read).
// XCD-affinity swizzle: bucket b's edata was written via XCD b%8's L2;
// remap physical block p so logical blocks 32b..32b+31 land on XCD b%8.
// ---------------------------------------------------------------------------
__global__ __launch_bounds__(256) void k_gather(
    const int* __restrict__ rowptr, const uint4* __restrict__ edata,
    const unsigned short* __restrict__ h_bf, const float* __restrict__ b,
    float* __restrict__ out)
{
    // physical -> logical: p on XCD p%8; want logical g with (g>>5)%8 == p%8
    const int p = blockIdx.x;                 // 0 .. GATHER_PB-1
    const int slot = p >> 3, k = p & 7;
    const int g = ((slot >> 5) << 8) + (k << 5) + (slot & 31);
    if (g >= GATHER_LB) return;

    int n = g * 4 + (threadIdx.x >> 6);
    if (n >= N_NODES) return;
    const int lane = threadIdx.x & 63;
    const int grp  = lane >> 4;    // group == output head at the end
    const int fq   = lane & 15;    // feature quad: feats fq*4 .. +3

    const int s0 = rowptr[n], s1 = rowptr[n + 1];
    const int nit = (s1 - s0 + 7) >> 3;

    float acc[4][4];
    #pragma unroll
    for (int hd = 0; hd < 4; ++hd)
        #pragma unroll
        for (int f = 0; f < 4; ++f) acc[hd][f] = 0.f;
    float den[4] = {0.f, 0.f, 0.f, 0.f};

    if (nit > 0) {   // s1 > s0 guaranteed inside
#define LOADE(ii, E0, E1)                                   \
        {                                                   \
            const int j0 = s0 + (ii) * 8 + 2 * grp;         \
            const int j1 = j0 + 1;                          \
            E0 = edata[j0 < s1 ? j0 : s1 - 1];              \
            E1 = edata[j1 < s1 ? j1 : s1 - 1];              \
            if (j0 >= s1) { E0.y = 0u; E0.z = 0u; }         \
            if (j1 >= s1) { E1.y = 0u; E1.z = 0u; }         \
        }
#define LOADH(E, H)                                                              \
        H = *(const uint2*)(h_bf + (((E.x & 0xFFFFu) << 6) + ((unsigned)fq << 2)));
#define COMP1(E, H)                                                              \
        {                                                                        \
            const float w0 = bf_lo(E.y), w1 = bf_hi(E.y);                        \
            const float w2 = bf_lo(E.z), w3 = bf_hi(E.z);                        \
            const float f0 = bf_lo(H.x), f1 = bf_hi(H.x);                        \
            const float f2 = bf_lo(H.y), f3 = bf_hi(H.y);                        \
            den[0] += w0; den[1] += w1; den[2] += w2; den[3] += w3;              \
            acc[0][0] += w0 * f0; acc[0][1] += w0 * f1;                          \
            acc[0][2] += w0 * f2; acc[0][3] += w0 * f3;                          \
            acc[1][0] += w1 * f0; acc[1][1] += w1 * f1;                          \
            acc[1][2] += w1 * f2; acc[1][3] += w1 * f3;                          \
            acc[2][0] += w2 * f0; acc[2][1] += w2 * f1;                          \
            acc[2][2] += w2 * f2; acc[2][3] += w2 * f3;                          \
            acc[3][0] += w3 * f0; acc[3][1] += w3 * f1;                          \
            acc[3][2] += w3 * f2; acc[3][3] += w3 * f3;                          \
        }

        uint4 a0, a1, b0, b1;
        uint2 ha0, ha1, hb0, hb1;
        LOADE(0, a0, a1);
        LOADH(a0, ha0); LOADH(a1, ha1);

        for (int it = 0; it < nit; ++it) {
            LOADE(it + 1, b0, b1);
            LOADH(b0, hb0); LOADH(b1, hb1);
            COMP1(a0, ha0);
            COMP1(a1, ha1);
            a0 = b0; a1 = b1; ha0 = hb0; ha1 = hb1;
        }
#undef LOADE
#undef LOADH
#undef COMP1
    }

    // reduce partials across the 4 groups (lanes xor 16, 32)
    #pragma unroll
    for (int hd = 0; hd < 4; ++hd) {
        float v = den[hd];
        v += __shfl_xor(v, 16); v += __shfl_xor(v, 32);
        den[hd] = v;
        #pragma unroll
        for (int f = 0; f < 4; ++f) {
            float u = acc[hd][f];
            u += __shfl_xor(u, 16); u += __shfl_xor(u, 32);
            acc[hd][f] = u;
        }
    }

    const float dg = grp == 0 ? den[0] : grp == 1 ? den[1] : grp == 2 ? den[2] : den[3];
    const float inv = 1.f / fmaxf(dg, EPS);
    f32x4 o;
    o.x = (grp == 0 ? acc[0][0] : grp == 1 ? acc[1][0] : grp == 2 ? acc[2][0] : acc[3][0]);
    o.y = (grp == 0 ? acc[0][1] : grp == 1 ? acc[1][1] : grp == 2 ? acc[2][1] : acc[3][1]);
    o.z = (grp == 0 ? acc[0][2] : grp == 1 ? acc[1][2] : grp == 2 ? acc[2][2] : acc[3][2]);
    o.w = (grp == 0 ? acc[0][3] : grp == 1 ? acc[1][3] : grp == 2 ? acc[2][3] : acc[3][3]);

    const float4 bias = *(const float4*)(b + fq * 4);
    o.x = o.x * inv + bias.x;
    o.y = o.y * inv + bias.y;
    o.z = o.z * inv + bias.z;
    o.w = o.w * inv + bias.w;
    __builtin_nontemporal_store(o,
        (f32x4*)(out + (size_t)n * (N_HEADS * OUT_F) + grp * 64 + fq * 4));
}

extern "C" void kernel_launch(void* const* d_in, const int* in_sizes, int n_in,
                              void* d_out, int out_size, void* d_ws, size_t ws_size,
                              hipStream_t stream)
{
    const float* x   = (const float*)d_in[0];
    const int*   ei  = (const int*)d_in[1];
    const float* W   = (const float*)d_in[2];
    const float* a_l = (const float*)d_in[3];
    const float* a_r = (const float*)d_in[4];
    const float* b   = (const float*)d_in[5];
    float* out = (float*)d_out;

    char* ws = (char*)d_ws;
    unsigned short* h_bf = (unsigned short*)(ws);          //  6,400,000 B
    float*    el       = (float*)   (ws +  6400000);       //    800,000 B
    float*    er       = (float*)   (ws +  7200000);       //    800,000 B
    int*      histG    = (int*)     (ws +  8000000);       //    306,544 B
    int*      scanHist = (int*)     (ws +  8306544);       //    306,544 B
    int*      blocksum = (int*)     (ws +  8613088);       //      1,024 B
    unsigned* ebuf     = (unsigned*)(ws +  8614112);       //  3,200,000 B
    int*      rowptr   = (int*)     (ws + 11814112);       //    200,016 B
    uint4*    edata    = (uint4*)   (ws + 12014128);       // 12,800,016 B
    // total: 24,814,144 B

    const int* row = ei;
    const int* col = ei + N_EDGES;

    k_hist_gemm  <<<NCH + NODE_BLOCKS, 256, 0, stream>>>(
                     x, W, a_l, a_r, row, histG, h_bf, el, er);
    k_scan2_local<<<S2B, 256, 0, stream>>>(histG, scanHist, blocksum);
    k_scatter    <<<NCH, 256, 0, stream>>>(row, col, scanHist, blocksum, ebuf);
    k_bucket     <<<NB, 256, 0, stream>>>(ebuf, scanHist, blocksum, el, er, rowptr, edata);
    k_gather     <<<GATHER_PB, 256, 0, stream>>>(rowptr, edata, h_bf, b, out);
}

// Round 18
// 76.292 us; speedup vs baseline: 2.0389x; 1.0065x over previous
//
#include <hip/hip_runtime.h>

#define N_NODES 50000
#define N_EDGES 800000
#define IN_F    128
#define OUT_F   64
#define N_HEADS 4
#define NEG_SLOPE 0.2f
#define EPS 1e-12f

#define NODE_BLOCKS 782   // ceil(50000 / 64) for the MFMA part
#define NB    391         // buckets of 128 rows: bucket = row >> 7
#define CHUNK 4096        // edges per histogram/scatter chunk
#define NCH   196         // 196*4096 = 802816 >= 800000
#define S2N   (NB * NCH)  // 76636 histogram entries
#define S2B   75          // scan blocks: 75*1024 = 76800 >= S2N
#define GATHER_LB 12500   // logical gather blocks = N_NODES/4
#define GATHER_PB 12544   // physical (padded to cover the swizzle range)

typedef __attribute__((ext_vector_type(8))) short bf16x8;
typedef __attribute__((ext_vector_type(4))) float f32x4;
typedef __attribute__((ext_vector_type(2))) float f32x2;

// bf16 helpers (RNE)
__device__ __forceinline__ unsigned short f2bf(float f) {
    unsigned int u = __float_as_uint(f);
    u += 0x7FFFu + ((u >> 16) & 1u);
    return (unsigned short)(u >> 16);
}
__device__ __forceinline__ f32x2 bfpair(unsigned u) {
    f32x2 r;
    r.x = __uint_as_float(u << 16);
    r.y = __uint_as_float(u & 0xFFFF0000u);
    return r;
}

// ---------------------------------------------------------------------------
// K1 fused: blocks [0, NCH): per-chunk bucket histogram (LDS atomics);
// blocks [NCH, NCH+NODE_BLOCKS): h = x@W via MFMA bf16 with fused el/er
// epilogue. W converted f32->bf16 in-block (no prep pass).
// LDS tiles bf16 [64][128], XOR-swizzled (byte ^= (row&7)<<4).
// MFMA C/D: col = l&15, row = (l>>4)*4 + reg  [verified mapping].
// ---------------------------------------------------------------------------
__global__ __launch_bounds__(256) void k_hist_gemm(
    const float* __restrict__ x, const float* __restrict__ W,
    const float* __restrict__ a_l, const float* __restrict__ a_r,
    const int* __restrict__ row, int* __restrict__ histG,
    unsigned short* __restrict__ h_bf,
    float* __restrict__ el, float* __restrict__ er)
{
    __shared__ int hist[NB];
    __shared__ unsigned short xs[64 * 128];   // 16 KB, swizzled
    __shared__ unsigned short wsh[64 * 128];  // 16 KB, swizzled
    const int tid = threadIdx.x;

    if (blockIdx.x < NCH) {
        // ---- histogram part ----
        const int ch = blockIdx.x;
        for (int i = tid; i < NB; i += 256) hist[i] = 0;
        __syncthreads();
        const int e0 = ch * CHUNK + tid * 16;
        #pragma unroll
        for (int q = 0; q < 4; ++q) {
            const int e = e0 + q * 4;
            if (e + 3 < N_EDGES) {
                int4 a = *(const int4*)(row + e);
                atomicAdd(&hist[a.x >> 7], 1); atomicAdd(&hist[a.y >> 7], 1);
                atomicAdd(&hist[a.z >> 7], 1); atomicAdd(&hist[a.w >> 7], 1);
            } else {
                #pragma unroll
                for (int j = 0; j < 4; ++j)
                    if (e + j < N_EDGES) atomicAdd(&hist[row[e + j] >> 7], 1);
            }
        }
        __syncthreads();
        for (int i = tid; i < NB; i += 256) histG[i * NCH + ch] = hist[i];
        return;
    }

    // ---- GEMM part ----
    const int node0 = (blockIdx.x - NCH) * 64;

    {   // stage W transposed+bf16+swizzled: thread t: col c = t&63, kq = t>>6
        const int c  = tid & 63;
        const int kq = tid >> 6;          // k-range kq*32 .. +31
        #pragma unroll
        for (int kb = 0; kb < 32; kb += 8) {
            unsigned pk[4];
            #pragma unroll
            for (int i = 0; i < 4; ++i) {
                const int k = kq * 32 + kb + 2 * i;
                const float v0 = W[k * OUT_F + c];        // wave-coalesced 256B
                const float v1 = W[(k + 1) * OUT_F + c];
                pk[i] = (unsigned)f2bf(v0) | ((unsigned)f2bf(v1) << 16);
            }
            const int cb = (kq * 32 + kb) * 2;            // byte col offset
            *(uint4*)((char*)wsh + c * 256 + (cb ^ ((c & 7) << 4))) =
                make_uint4(pk[0], pk[1], pk[2], pk[3]);
        }
    }
    {   // stage x rows (f32 -> bf16)
        const int r = tid >> 2;
        const int c0 = (tid & 3) * 32;
        const int node = node0 + r;
        unsigned int pk[16];
        if (node < N_NODES) {
            const float* src = x + (size_t)node * IN_F + c0;
            #pragma unroll
            for (int i = 0; i < 8; ++i) {
                float4 v = *(const float4*)(src + 4 * i);
                pk[2 * i + 0] = (unsigned)f2bf(v.x) | ((unsigned)f2bf(v.y) << 16);
                pk[2 * i + 1] = (unsigned)f2bf(v.z) | ((unsigned)f2bf(v.w) << 16);
            }
        } else {
            #pragma unroll
            for (int i = 0; i < 16; ++i) pk[i] = 0;
        }
        #pragma unroll
        for (int q = 0; q < 4; ++q) {
            int cb = c0 * 2 + q * 16;
            *(uint4*)((char*)xs + r * 256 + (cb ^ ((r & 7) << 4))) =
                make_uint4(pk[4 * q], pk[4 * q + 1], pk[4 * q + 2], pk[4 * q + 3]);
        }
    }
    __syncthreads();

    const int w  = tid >> 6, l = tid & 63;
    const int lr = l & 15, lg = l >> 4;
    const int arow = w * 16 + lr;

    bf16x8 afr[4];
    #pragma unroll
    for (int t = 0; t < 4; ++t) {
        int cb = t * 64 + lg * 16;
        afr[t] = *(const bf16x8*)((char*)xs + arow * 256 + (cb ^ ((arow & 7) << 4)));
    }

    const f32x4 zero = {0.f, 0.f, 0.f, 0.f};
    f32x4 acc[4] = {zero, zero, zero, zero};
    #pragma unroll
    for (int nt = 0; nt < 4; ++nt) {
        const int brow = nt * 16 + lr;
        #pragma unroll
        for (int t = 0; t < 4; ++t) {
            int cb = t * 64 + lg * 16;
            bf16x8 bfr = *(const bf16x8*)((char*)wsh + brow * 256 + (cb ^ ((brow & 7) << 4)));
            acc[nt] = __builtin_amdgcn_mfma_f32_16x16x32_bf16(afr[t], bfr, acc[nt], 0, 0, 0);
        }
    }

    #pragma unroll
    for (int r = 0; r < 4; ++r) {
        const int node = node0 + w * 16 + lg * 4 + r;
        if (node < N_NODES) {
            #pragma unroll
            for (int nt = 0; nt < 4; ++nt)
                h_bf[(size_t)node * OUT_F + nt * 16 + lr] = f2bf(acc[nt][r]);
        }
    }

    float4 al4[4], ar4[4];
    #pragma unroll
    for (int nt = 0; nt < 4; ++nt) {
        al4[nt] = *(const float4*)(a_l + (size_t)(nt * 16 + lr) * N_HEADS);
        ar4[nt] = *(const float4*)(a_r + (size_t)(nt * 16 + lr) * N_HEADS);
    }
    #pragma unroll
    for (int r = 0; r < 4; ++r) {
        float4 pl = make_float4(0.f, 0.f, 0.f, 0.f);
        float4 pr = make_float4(0.f, 0.f, 0.f, 0.f);
        #pragma unroll
        for (int nt = 0; nt < 4; ++nt) {
            const float v = acc[nt][r];
            pl.x += v * al4[nt].x; pl.y += v * al4[nt].y;
            pl.z += v * al4[nt].z; pl.w += v * al4[nt].w;
            pr.x += v * ar4[nt].x; pr.y += v * ar4[nt].y;
            pr.z += v * ar4[nt].z; pr.w += v * ar4[nt].w;
        }
        #pragma unroll
        for (int off = 1; off < 16; off <<= 1) {
            pl.x += __shfl_xor(pl.x, off); pl.y += __shfl_xor(pl.y, off);
            pl.z += __shfl_xor(pl.z, off); pl.w += __shfl_xor(pl.w, off);
            pr.x += __shfl_xor(pr.x, off); pr.y += __shfl_xor(pr.y, off);
            pr.z += __shfl_xor(pr.z, off); pr.w += __shfl_xor(pr.w, off);
        }
        const int node = node0 + w * 16 + lg * 4 + r;
        if (lr == 0 && node < N_NODES) {
            *(float4*)(el + (size_t)node * N_HEADS) = pl;
            *(float4*)(er + (size_t)node * N_HEADS) = pr;
        }
    }
}

// ---------------------------------------------------------------------------
// S2a: per-block exclusive scan (1024 elems/block) of histG -> scanHist.
// Consumers (scatter, bucket) apply the blocksum prefix themselves.
// ---------------------------------------------------------------------------
__global__ __launch_bounds__(256) void k_scan2_local(
    const int* __restrict__ histG, int* __restrict__ scanHist,
    int* __restrict__ blocksum)
{
    __shared__ int wsum[4];
    const int t = threadIdx.x;
    const int base = blockIdx.x * 1024 + t * 4;

    int4 d = make_int4(0, 0, 0, 0);
    if (base + 3 < S2N) d = *(const int4*)(histG + base);
    else {
        if (base + 0 < S2N) d.x = histG[base + 0];
        if (base + 1 < S2N) d.y = histG[base + 1];
        if (base + 2 < S2N) d.z = histG[base + 2];
        if (base + 3 < S2N) d.w = histG[base + 3];
    }
    const int tsum = d.x + d.y + d.z + d.w;

    const int lane = t & 63, wave = t >> 6;
    int inc = tsum;
    #pragma unroll
    for (int off = 1; off < 64; off <<= 1) {
        int v = __shfl_up(inc, off);
        if (lane >= off) inc += v;
    }
    if (lane == 63) wsum[wave] = inc;
    __syncthreads();

    int woff = 0;
    #pragma unroll
    for (int w = 0; w < 4; ++w) woff += (w < wave) ? wsum[w] : 0;

    const int ex = woff + inc - tsum;
    int4 o;
    o.x = ex; o.y = ex + d.x; o.z = o.y + d.y; o.w = o.z + d.z;
    if (base + 3 < S2N) *(int4*)(scanHist + base) = o;
    else {
        if (base + 0 < S2N) scanHist[base + 0] = o.x;
        if (base + 1 < S2N) scanHist[base + 1] = o.y;
        if (base + 2 < S2N) scanHist[base + 2] = o.z;
        if (base + 3 < S2N) scanHist[base + 3] = o.w;
    }
    if (t == 0) blocksum[blockIdx.x] = wsum[0] + wsum[1] + wsum[2] + wsum[3];
}

// ---------------------------------------------------------------------------
// S3: bucket-scatter edges. Per chunk: LDS write cursors from scanHist +
// blocksum prefix (computed in LDS), LDS-atomic slot allocation, store
// packed (row&127)<<17 | col.
// ---------------------------------------------------------------------------
__global__ __launch_bounds__(256) void k_scatter(
    const int* __restrict__ row, const int* __restrict__ col,
    const int* __restrict__ scanHist, const int* __restrict__ blocksum,
    unsigned* __restrict__ ebuf)
{
    __shared__ int off[NB];
    __shared__ int bsum[S2B];
    const int ch = blockIdx.x;
    const int t = threadIdx.x;
    if (t < S2B) bsum[t] = blocksum[t];
    __syncthreads();
    if (t == 0) {
        int s = 0;
        for (int i = 0; i < S2B; ++i) { int v = bsum[i]; bsum[i] = s; s += v; }
    }
    __syncthreads();
    for (int i = t; i < NB; i += 256) {
        const int idx = i * NCH + ch;
        off[i] = scanHist[idx] + bsum[idx >> 10];
    }
    __syncthreads();
    const int e0 = ch * CHUNK;
    #pragma unroll
    for (int k = 0; k < 16; ++k) {
        const int e = e0 + t + k * 256;
        if (e < N_EDGES) {
            const int r = row[e], c = col[e];
            const int pos = atomicAdd(&off[r >> 7], 1);
            ebuf[pos] = ((unsigned)(r & 127) << 17) | (unsigned)c;
        }
    }
}

// ---------------------------------------------------------------------------
// S4: per-bucket CSR finalize. Count 128 local rows (LDS), scan, write
// rowptr; then scatter packed edge records {col, w01(bf16), w23(bf16), 0}
// into the bucket-local region (single block -> single XCD).
// ---------------------------------------------------------------------------
__global__ __launch_bounds__(256) void k_bucket(
    const unsigned* __restrict__ ebuf, const int* __restrict__ scanHist,
    const int* __restrict__ blocksum,
    const float* __restrict__ el, const float* __restrict__ er,
    int* __restrict__ rowptr, uint4* __restrict__ edata)
{
    __shared__ float4 elv[128];
    __shared__ int cnt[128];
    __shared__ int wsum2[2];
    __shared__ int bsum[S2B];
    const int b = blockIdx.x;
    const int t = threadIdx.x;
    const int node0 = b << 7;

    if (t < S2B) bsum[t] = blocksum[t];
    __syncthreads();
    if (t == 0) {
        int s = 0;
        for (int i = 0; i < S2B; ++i) { int v = bsum[i]; bsum[i] = s; s += v; }
    }
    __syncthreads();

    const int i0 = b * NCH;
    const int base = scanHist[i0] + bsum[i0 >> 10];
    int end;
    if (b < NB - 1) {
        const int i1 = (b + 1) * NCH;
        end = scanHist[i1] + bsum[i1 >> 10];
    } else end = N_EDGES;

    if (t < 128) {
        const int node = node0 + t;
        elv[t] = (node < N_NODES) ? *(const float4*)(el + node * 4)
                                  : make_float4(0.f, 0.f, 0.f, 0.f);
        cnt[t] = 0;
    }
    __syncthreads();
    for (int i = base + t; i < end; i += 256)
        atomicAdd(&cnt[ebuf[i] >> 17], 1);
    __syncthreads();

    int inc = 0, val = 0;
    const int lane = t & 63, wave = t >> 6;
    if (t < 128) {
        val = cnt[t];
        inc = val;
        #pragma unroll
        for (int off = 1; off < 64; off <<= 1) {
            int v = __shfl_up(inc, off);
            if (lane >= off) inc += v;
        }
        if (lane == 63) wsum2[wave] = inc;
    }
    __syncthreads();
    int excl = 0;
    if (t < 128) {
        const int woff = (wave == 1) ? wsum2[0] : 0;
        excl = base + woff + inc - val;
        const int node = node0 + t;
        if (node < N_NODES) rowptr[node] = excl;
    }
    if (b == NB - 1 && t == 0) rowptr[N_NODES] = N_EDGES;
    __syncthreads();
    if (t < 128) cnt[t] = excl;   // reuse as write cursors
    __syncthreads();

    for (int i = base + t; i < end; i += 256) {
        const unsigned p = ebuf[i];
        const int r = p >> 17;
        const int c = (int)(p & 0x1FFFFu);
        const int pos = atomicAdd(&cnt[r], 1);
        const float4 e4 = elv[r];
        const float4 r4 = *(const float4*)(er + ((unsigned)c << 2));
        float s0 = e4.x + r4.x, s1 = e4.y + r4.y;
        float s2 = e4.z + r4.z, s3 = e4.w + r4.w;
        s0 = s0 > 0.f ? s0 : NEG_SLOPE * s0;
        s1 = s1 > 0.f ? s1 : NEG_SLOPE * s1;
        s2 = s2 > 0.f ? s2 : NEG_SLOPE * s2;
        s3 = s3 > 0.f ? s3 : NEG_SLOPE * s3;
        const unsigned w01 = (unsigned)f2bf(__expf(s0)) | ((unsigned)f2bf(__expf(s1)) << 16);
        const unsigned w23 = (unsigned)f2bf(__expf(s2)) | ((unsigned)f2bf(__expf(s3)) << 16);
        edata[pos] = make_uint4((unsigned)c, w01, w23, 0u);
    }
}

// ---------------------------------------------------------------------------
// K5: gather — one wave per node; 4 x 16-lane groups, 2 edges per group per
// iteration (8/wave-iter), 1-ahead pipeline, branch-free clamped loads.
// Accumulation in packed f32x2 (v_pk_* on CDNA4 halves VALU issue slots).
// Edge record: uint4 {col, w01 bf16x2, w23 bf16x2, 0} (plain loads: L2-warm
// from k_bucket). out stores nontemporal (never re-read).
// XCD-affinity swizzle: logical blocks 32b..32b+31 land on XCD b%8.
// ---------------------------------------------------------------------------
__global__ __launch_bounds__(256) void k_gather(
    const int* __restrict__ rowptr, const uint4* __restrict__ edata,
    const unsigned short* __restrict__ h_bf, const float* __restrict__ b,
    float* __restrict__ out)
{
    const int p = blockIdx.x;                 // 0 .. GATHER_PB-1
    const int slot = p >> 3, k = p & 7;
    const int g = ((slot >> 5) << 8) + (k << 5) + (slot & 31);
    if (g >= GATHER_LB) return;

    int n = g * 4 + (threadIdx.x >> 6);
    if (n >= N_NODES) return;
    const int lane = threadIdx.x & 63;
    const int grp  = lane >> 4;    // group == output head at the end
    const int fq   = lane & 15;    // feature quad: feats fq*4 .. +3

    const int s0 = rowptr[n], s1 = rowptr[n + 1];
    const int nit = (s1 - s0 + 7) >> 3;

    const f32x2 z2 = {0.f, 0.f};
    f32x2 acc01[4] = {z2, z2, z2, z2};   // features (fq*4+0, fq*4+1) x 4 heads
    f32x2 acc23[4] = {z2, z2, z2, z2};   // features (fq*4+2, fq*4+3) x 4 heads
    f32x2 den01 = z2, den23 = z2;

    if (nit > 0) {   // s1 > s0 guaranteed inside
#define LOADE(ii, E0, E1)                                   \
        {                                                   \
            const int j0 = s0 + (ii) * 8 + 2 * grp;         \
            const int j1 = j0 + 1;                          \
            E0 = edata[j0 < s1 ? j0 : s1 - 1];              \
            E1 = edata[j1 < s1 ? j1 : s1 - 1];              \
            if (j0 >= s1) { E0.y = 0u; E0.z = 0u; }         \
            if (j1 >= s1) { E1.y = 0u; E1.z = 0u; }         \
        }
#define LOADH(E, H)                                                              \
        H = *(const uint2*)(h_bf + (((E.x & 0xFFFFu) << 6) + ((unsigned)fq << 2)));
#define COMP1(E, H)                                                              \
        {                                                                        \
            const f32x2 wp01 = bfpair(E.y);                                      \
            const f32x2 wp23 = bfpair(E.z);                                      \
            const f32x2 h01  = bfpair(H.x);                                      \
            const f32x2 h23  = bfpair(H.y);                                      \
            den01 += wp01; den23 += wp23;                                        \
            const f32x2 w00 = {wp01.x, wp01.x};                                  \
            const f32x2 w11 = {wp01.y, wp01.y};                                  \
            const f32x2 w22 = {wp23.x, wp23.x};                                  \
            const f32x2 w33 = {wp23.y, wp23.y};                                  \
            acc01[0] += w00 * h01; acc23[0] += w00 * h23;                        \
            acc01[1] += w11 * h01; acc23[1] += w11 * h23;                        \
            acc01[2] += w22 * h01; acc23[2] += w22 * h23;                        \
            acc01[3] += w33 * h01; acc23[3] += w33 * h23;                        \
        }

        uint4 a0, a1, b0, b1;
        uint2 ha0, ha1, hb0, hb1;
        LOADE(0, a0, a1);
        LOADH(a0, ha0); LOADH(a1, ha1);

        for (int it = 0; it < nit; ++it) {
            LOADE(it + 1, b0, b1);
            LOADH(b0, hb0); LOADH(b1, hb1);
            COMP1(a0, ha0);
            COMP1(a1, ha1);
            a0 = b0; a1 = b1; ha0 = hb0; ha1 = hb1;
        }
#undef LOADE
#undef LOADH
#undef COMP1
    }

    // unpack to scalars, then reduce partials across the 4 groups
    float den[4] = {den01.x, den01.y, den23.x, den23.y};
    float acc[4][4];
    #pragma unroll
    for (int hd = 0; hd < 4; ++hd) {
        acc[hd][0] = acc01[hd].x; acc[hd][1] = acc01[hd].y;
        acc[hd][2] = acc23[hd].x; acc[hd][3] = acc23[hd].y;
    }

    #pragma unroll
    for (int hd = 0; hd < 4; ++hd) {
        float v = den[hd];
        v += __shfl_xor(v, 16); v += __shfl_xor(v, 32);
        den[hd] = v;
        #pragma unroll
        for (int f = 0; f < 4; ++f) {
            float u = acc[hd][f];
            u += __shfl_xor(u, 16); u += __shfl_xor(u, 32);
            acc[hd][f] = u;
        }
    }

    const float dg = grp == 0 ? den[0] : grp == 1 ? den[1] : grp == 2 ? den[2] : den[3];
    const float inv = 1.f / fmaxf(dg, EPS);
    f32x4 o;
    o.x = (grp == 0 ? acc[0][0] : grp == 1 ? acc[1][0] : grp == 2 ? acc[2][0] : acc[3][0]);
    o.y = (grp == 0 ? acc[0][1] : grp == 1 ? acc[1][1] : grp == 2 ? acc[2][1] : acc[3][1]);
    o.z = (grp == 0 ? acc[0][2] : grp == 1 ? acc[1][2] : grp == 2 ? acc[2][2] : acc[3][2]);
    o.w = (grp == 0 ? acc[0][3] : grp == 1 ? acc[1][3] : grp == 2 ? acc[2][3] : acc[3][3]);

    const float4 bias = *(const float4*)(b + fq * 4);
    o.x = o.x * inv + bias.x;
    o.y = o.y * inv + bias.y;
    o.z = o.z * inv + bias.z;
    o.w = o.w * inv + bias.w;
    __builtin_nontemporal_store(o,
        (f32x4*)(out + (size_t)n * (N_HEADS * OUT_F) + grp * 64 + fq * 4));
}

extern "C" void kernel_launch(void* const* d_in, const int* in_sizes, int n_in,
                              void* d_out, int out_size, void* d_ws, size_t ws_size,
                              hipStream_t stream)
{
    const float* x   = (const float*)d_in[0];
    const int*   ei  = (const int*)d_in[1];
    const float* W   = (const float*)d_in[2];
    const float* a_l = (const float*)d_in[3];
    const float* a_r = (const float*)d_in[4];
    const float* b   = (const float*)d_in[5];
    float* out = (float*)d_out;

    char* ws = (char*)d_ws;
    unsigned short* h_bf = (unsigned short*)(ws);          //  6,400,000 B
    float*    el       = (float*)   (ws +  6400000);       //    800,000 B
    float*    er       = (float*)   (ws +  7200000);       //    800,000 B
    int*      histG    = (int*)     (ws +  8000000);       //    306,544 B
    int*      scanHist = (int*)     (ws +  8306544);       //    306,544 B
    int*      blocksum = (int*)     (ws +  8613088);       //      1,024 B
    unsigned* ebuf     = (unsigned*)(ws +  8614112);       //  3,200,000 B
    int*      rowptr   = (int*)     (ws + 11814112);       //    200,016 B
    uint4*    edata    = (uint4*)   (ws + 12014128);       // 12,800,016 B
    // total: 24,814,144 B

    const int* row = ei;
    const int* col = ei + N_EDGES;

    k_hist_gemm  <<<NCH + NODE_BLOCKS, 256, 0, stream>>>(
                     x, W, a_l, a_r, row, histG, h_bf, el, er);
    k_scan2_local<<<S2B, 256, 0, stream>>>(histG, scanHist, blocksum);
    k_scatter    <<<NCH, 256, 0, stream>>>(row, col, scanHist, blocksum, ebuf);
    k_bucket     <<<NB, 256, 0, stream>>>(ebuf, scanHist, blocksum, el, er, rowptr, edata);
    k_gather     <<<GATHER_PB, 256, 0, stream>>>(rowptr, edata, h_bf, b, out);
}